// Round 12
// baseline (787.559 us; speedup 1.0000x reference)
//
#include <hip/hip_runtime.h>
#include <cstdint>
#include <cstddef>

// ---------------------------------------------------------------------------
// TransformerMultiViewFusion (MI355X / gfx950), round 12.
//
//  R12 extends R11's validated pattern (fragment-direct B-operands + unroll
//  cap => no spill, no staging barriers) to:
//   * ffn v7: phase A now W1F fragment-direct too (unroll 2). No weight LDS
//     at all: 48KB (Xs+Ts), barriers 33->17/block.
//   * gemm_qkv_k: A staged once (1 barrier), Wqkv fragments direct (unroll 2).
//  gemm_ln (Wo) and input gemm_bt unchanged. Tripwires: WRITE_SIZE per kernel
//  (ffn >45MB / qkv >68MB => spill => revert that kernel).
//
//  Workspace: X@0 | QKV@37748736 | SA@150994944 | Xf@188743680 |
//   WpB@198180864 | W2F@198213632 | W1F@199262208 | WqkvF@200310784 |
//   WoB@226492416
// ---------------------------------------------------------------------------

typedef __bf16 bf16;
typedef __bf16 bf16x8 __attribute__((ext_vector_type(8)));
typedef __bf16 bf16x4 __attribute__((ext_vector_type(4)));
typedef float  f32x4  __attribute__((ext_vector_type(4)));

__device__ __forceinline__ void async_copy16(const void* g, void* l)
{
    __builtin_amdgcn_global_load_lds(
        (__attribute__((address_space(1))) void*)g,
        (__attribute__((address_space(3))) void*)l,
        16, 0, 0);
}

// --------------------------------------------------------------------------
// row-major packs still needed: Wo (131072) + Wp (16384). 576 blocks.
// --------------------------------------------------------------------------
__global__ void pack_all_k(const float* __restrict__ Wo, const float* __restrict__ Wp,
                           bf16* __restrict__ WoB, bf16* __restrict__ WpB)
{
    const int i = blockIdx.x * 256 + threadIdx.x;
    if (i < 131072)      WoB[i] = (bf16)Wo[i];
    else if (i < 147456) WpB[i - 131072] = (bf16)Wp[i - 131072];
}

// --------------------------------------------------------------------------
// fragment packs: W1 (2x32768 entries), W2 (2x32768), Wqkv (2x24576).
// Entry e of [N x K]: nt=e/perNT, kc=(e%perNT)>>6, lane=e&63, holds
// W[nt*16+(lane&15)][kc*32+(lane>>4)*8 .. +8].  704 blocks.
// --------------------------------------------------------------------------
__global__ void pack_frag_k(const float* __restrict__ W1, const float* __restrict__ W2,
                            const float* __restrict__ Wqkv,
                            bf16* __restrict__ W1F, bf16* __restrict__ W2F,
                            bf16* __restrict__ WqkvF)
{
    const int g = blockIdx.x * 256 + threadIdx.x;   // 0..180223
    const float* src; bf16* dst; int K, e;
    if (g < 65536)       { const int l = g >> 15; e = g & 32767; K = 256;
                           src = W1 + (size_t)l * 262144;  dst = W1F + (size_t)l * 262144; }
    else if (g < 131072) { const int r = g - 65536; const int l = r >> 15; e = r & 32767; K = 1024;
                           src = W2 + (size_t)l * 262144;  dst = W2F + (size_t)l * 262144; }
    else if (g < 180224) { const int r = g - 131072; const int l = r / 24576; e = r % 24576; K = 256;
                           src = Wqkv + (size_t)l * 196608; dst = WqkvF + (size_t)l * 196608; }
    else return;

    const int perNT = (K >> 5) << 6;
    const int nt   = e / perNT;
    const int rem  = e % perNT;
    const int kc   = rem >> 6;
    const int lane = rem & 63;
    const int row  = nt * 16 + (lane & 15);
    const int col  = kc * 32 + (lane >> 4) * 8;
    bf16x8 v;
#pragma unroll
    for (int q = 0; q < 8; ++q) v[q] = (bf16)src[(size_t)row * K + col + q];
    *(bf16x8*)(dst + (size_t)e * 8) = v;
}

// --------------------------------------------------------------------------
// feat transpose-pack: Xf[t][c] = (bf16)feat[cam][b][c][hw]
// --------------------------------------------------------------------------
__global__ __launch_bounds__(256) void feat_pack_k(const float* __restrict__ feat,
                                                   bf16* __restrict__ Xf)
{
    __shared__ float ft[64][68];

    const int tid  = threadIdx.x;
    const int camb = blockIdx.y;
    const int cam  = camb >> 1;
    const int b    = camb & 1;
    const int hw0  = blockIdx.x * 64;

    const float* fb = feat + (size_t)camb * 64 * 9216 + hw0;
#pragma unroll
    for (int rep = 0; rep < 16; ++rep) {
        const int idx = rep * 256 + tid;
        const int c = idx >> 6, p = idx & 63;
        ft[p][c] = fb[(size_t)c * 9216 + p];
    }
    __syncthreads();

    const int pbase = b * 9216 + hw0;
#pragma unroll
    for (int rep = 0; rep < 2; ++rep) {
        const int idx = rep * 256 + tid;
        const int p = idx >> 3, cc = idx & 7;
        const f32x4 a = *(const f32x4*)(&ft[p][cc * 8]);
        const f32x4 c4 = *(const f32x4*)(&ft[p][cc * 8 + 4]);
        bf16x8 v;
#pragma unroll
        for (int i = 0; i < 4; ++i) { v[i] = (bf16)a[i]; v[4 + i] = (bf16)c4[i]; }
        const size_t t = (size_t)(pbase + p) * 4 + cam;
        *(bf16x8*)(Xf + t * 64 + cc * 8) = v;
    }
}

// --------------------------------------------------------------------------
// GEMM-BT (input proj only): C = A@B^T + bias. 128x128 tile, K=64.
// --------------------------------------------------------------------------
template <bool RELU>
__global__ __launch_bounds__(256, 2) void gemm_bt(
    const bf16* __restrict__ A, const bf16* __restrict__ B,
    const float* __restrict__ bias, bf16* __restrict__ C,
    int N, int K)
{
    __shared__ __align__(16) bf16 As[128 * 64];
    __shared__ __align__(16) bf16 Bs[128 * 64];

    const int tid  = threadIdx.x;
    const int lane = tid & 63;
    const int wv   = tid >> 6;
    const int wm   = wv >> 1;
    const int wn   = wv & 1;
    const int bm   = blockIdx.y * 128;
    const int bn   = blockIdx.x * 128;

    const int r8  = lane >> 3;
    const int p8  = lane & 7;
    const int gch = p8 ^ r8;

    const int quad = lane >> 4;
    const int l16  = lane & 15;

    f32x4 acc[4][4] = {};

    for (int k0 = 0; k0 < K; k0 += 64) {
#pragma unroll
        for (int inst = 0; inst < 4; ++inst) {
            const int row = wv * 32 + inst * 8 + r8;
            const bf16* ga = A + (size_t)(bm + row) * K + (k0 + gch * 8);
            const bf16* gb = B + (size_t)(bn + row) * K + (k0 + gch * 8);
            async_copy16(ga, (char*)As + (wv * 4 + inst) * 1024);
            async_copy16(gb, (char*)Bs + (wv * 4 + inst) * 1024);
        }
        __syncthreads();

#pragma unroll
        for (int kk = 0; kk < 2; ++kk) {
            bf16x8 af[4], bfr[4];
            const int lch = kk * 4 + quad;
#pragma unroll
            for (int i = 0; i < 4; ++i) {
                const int m = wm * 64 + i * 16 + l16;
                af[i] = *(const bf16x8*)((const char*)As + (m * 8 + (lch ^ (m & 7))) * 16);
                const int n = wn * 64 + i * 16 + l16;
                bfr[i] = *(const bf16x8*)((const char*)Bs + (n * 8 + (lch ^ (n & 7))) * 16);
            }
#pragma unroll
            for (int i = 0; i < 4; ++i)
#pragma unroll
                for (int j = 0; j < 4; ++j)
                    acc[i][j] = __builtin_amdgcn_mfma_f32_16x16x32_bf16(
                        af[i], bfr[j], acc[i][j], 0, 0, 0);
        }
        __syncthreads();
    }

#pragma unroll
    for (int j = 0; j < 4; ++j) {
        const int n = bn + wn * 64 + j * 16 + l16;
        const float bv = bias[n];
#pragma unroll
        for (int i = 0; i < 4; ++i) {
            const int mb = bm + wm * 64 + i * 16 + quad * 4;
#pragma unroll
            for (int r = 0; r < 4; ++r) {
                float v = acc[i][j][r] + bv;
                if (RELU) v = fmaxf(v, 0.f);
                C[(size_t)(mb + r) * N + n] = (bf16)v;
            }
        }
    }
}

// --------------------------------------------------------------------------
// gemm_qkv_k: QKV[M,768] = X[M,256] @ WqkvF + bias. 128x128 tile.
// A staged once (1 barrier); B fragments direct from global, unroll 2.
// --------------------------------------------------------------------------
__global__ __launch_bounds__(256, 2) void gemm_qkv_k(
    const bf16* __restrict__ A, const bf16* __restrict__ Bf,
    const float* __restrict__ bias, bf16* __restrict__ C)
{
    __shared__ __align__(16) char As[65536];       // 128 x 256 bf16, 32 slots/row

    const int tid  = threadIdx.x;
    const int lane = tid & 63;
    const int wv   = tid >> 6;
    const int wm   = wv >> 1;
    const int wn   = wv & 1;
    const int bm   = blockIdx.y * 128;
    const int bn   = blockIdx.x * 128;
    const int nt0  = blockIdx.x * 8;
    const int quad = lane >> 4;
    const int l16  = lane & 15;

#pragma unroll
    for (int it = 0; it < 16; ++it) {
        const int L = it * 256 + tid;
        const int row = L >> 5, s = L & 31;
        const int c = (s & 24) | ((s ^ row) & 7);
        async_copy16(A + (size_t)(bm + row) * 256 + c * 8, As + (size_t)L * 16);
    }
    __syncthreads();

    f32x4 acc[4][4] = {};

#pragma unroll 2
    for (int kk = 0; kk < 8; ++kk) {
        bf16x8 af[4], bfr[4];
        const int gc = kk * 4 + quad;
#pragma unroll
        for (int i = 0; i < 4; ++i) {
            const int m  = wm * 64 + i * 16 + l16;
            const int sl = (gc & 24) | ((gc ^ m) & 7);
            af[i] = *(const bf16x8*)(As + (size_t)(m * 32 + sl) * 16);
        }
#pragma unroll
        for (int j = 0; j < 4; ++j) {
            const int nt = nt0 + wn * 4 + j;
            bfr[j] = *(const bf16x8*)(Bf + ((size_t)(nt * 8 + kk) * 64 + lane) * 8);
        }
#pragma unroll
        for (int i = 0; i < 4; ++i)
#pragma unroll
            for (int j = 0; j < 4; ++j)
                acc[i][j] = __builtin_amdgcn_mfma_f32_16x16x32_bf16(
                    af[i], bfr[j], acc[i][j], 0, 0, 0);
    }

#pragma unroll
    for (int j = 0; j < 4; ++j) {
        const int n = bn + wn * 64 + j * 16 + l16;
        const float bv = bias[n];
#pragma unroll
        for (int i = 0; i < 4; ++i) {
            const int mb = bm + wm * 64 + i * 16 + quad * 4;
#pragma unroll
            for (int r = 0; r < 4; ++r)
                C[(size_t)(mb + r) * 768 + n] = (bf16)(acc[i][j][r] + bv);
        }
    }
}

// --------------------------------------------------------------------------
// GEMM-BT + bias + residual + LayerNorm (Wo path, K=256). 128x256 tile.
// --------------------------------------------------------------------------
__global__ __launch_bounds__(256, 2) void gemm_ln_k(
    const bf16* __restrict__ A, const bf16* __restrict__ B,
    const float* __restrict__ bias, const bf16* __restrict__ Xres,
    const float* __restrict__ gam, const float* __restrict__ bet,
    bf16* __restrict__ Xout, int K)
{
    __shared__ __align__(16) bf16 S[24576];
    __shared__ float2 red[128][2];

    const int tid  = threadIdx.x;
    const int lane = tid & 63;
    const int wv   = tid >> 6;
    const int wm   = wv >> 1;
    const int wn   = wv & 1;
    const int bm   = blockIdx.x * 128;
    const int quad = lane >> 4;
    const int l16  = lane & 15;

    f32x4 acc[4][8] = {};

    for (int k0 = 0; k0 < K; k0 += 64) {
#pragma unroll
        for (int s = 0; s < 12; ++s) {
            const int L   = s * 256 + tid;
            const int row = L >> 3;
            const int gch = (L & 7) ^ (row & 7);
            const bf16* g = (row < 128)
                ? A + (size_t)(bm + row) * K + (k0 + gch * 8)
                : B + (size_t)(row - 128) * K + (k0 + gch * 8);
            async_copy16(g, (char*)S + (size_t)L * 16);
        }
        __syncthreads();

#pragma unroll
        for (int kk = 0; kk < 2; ++kk) {
            const int lch = kk * 4 + quad;
            bf16x8 af[4], bfr[8];
#pragma unroll
            for (int i = 0; i < 4; ++i) {
                const int m = wm * 64 + i * 16 + l16;
                af[i] = *(const bf16x8*)((const char*)S + (m * 8 + (lch ^ (m & 7))) * 16);
            }
#pragma unroll
            for (int j = 0; j < 8; ++j) {
                const int n = wn * 128 + j * 16 + l16;
                bfr[j] = *(const bf16x8*)((const char*)S + ((128 + n) * 8 + (lch ^ (n & 7))) * 16);
            }
#pragma unroll
            for (int i = 0; i < 4; ++i)
#pragma unroll
                for (int j = 0; j < 8; ++j)
                    acc[i][j] = __builtin_amdgcn_mfma_f32_16x16x32_bf16(
                        af[i], bfr[j], acc[i][j], 0, 0, 0);
        }
        __syncthreads();
    }

    float bv[8], gv[8], bev[8];
#pragma unroll
    for (int j = 0; j < 8; ++j) {
        const int n = wn * 128 + j * 16 + l16;
        bv[j] = bias[n]; gv[j] = gam[n]; bev[j] = bet[n];
    }

#pragma unroll
    for (int i = 0; i < 4; ++i) {
#pragma unroll
        for (int r = 0; r < 4; ++r) {
            const int rl  = wm * 64 + i * 16 + quad * 4 + r;
            const size_t row = (size_t)(bm + rl);
            float s1 = 0.f, s2 = 0.f;
#pragma unroll
            for (int j = 0; j < 8; ++j) {
                const int n = wn * 128 + j * 16 + l16;
                const float v = acc[i][j][r] + bv[j] + (float)Xres[row * 256 + n];
                acc[i][j][r] = v;
                s1 += v; s2 += v * v;
            }
#pragma unroll
            for (int off = 1; off < 16; off <<= 1) {
                s1 += __shfl_xor(s1, off, 64);
                s2 += __shfl_xor(s2, off, 64);
            }
            if (l16 == 0) red[rl][wn] = make_float2(s1, s2);
        }
    }
    __syncthreads();

#pragma unroll
    for (int i = 0; i < 4; ++i) {
#pragma unroll
        for (int r = 0; r < 4; ++r) {
            const int rl = wm * 64 + i * 16 + quad * 4 + r;
            const float2 p0 = red[rl][0], p1 = red[rl][1];
            const float mu  = (p0.x + p1.x) * (1.f / 256.f);
            const float ex2 = (p0.y + p1.y) * (1.f / 256.f);
            const float rstd = rsqrtf(fmaxf(ex2 - mu * mu, 0.f) + 1e-5f);
            const size_t row = (size_t)(bm + rl);
#pragma unroll
            for (int j = 0; j < 8; ++j) {
                const int n = wn * 128 + j * 16 + l16;
                Xout[row * 256 + n] = (bf16)((acc[i][j][r] - mu) * rstd * gv[j] + bev[j]);
            }
        }
    }
}

// --------------------------------------------------------------------------
// Fused FFN v7: both phases fragment-direct (unroll 2), no weight LDS.
// 64-row tile, grid 1152, waves 2x2. LDS: Xs 32K + Ts 16K (red aliases).
// Barriers: 1 + 2/hc = 17.
// --------------------------------------------------------------------------
__global__ __launch_bounds__(256, 2) void ffn_fused_k(
    const bf16* __restrict__ X,
    const bf16* __restrict__ W1f, const float* __restrict__ b1,
    const bf16* __restrict__ W2f, const float* __restrict__ b2,
    const float* __restrict__ gam, const float* __restrict__ bet,
    bf16* __restrict__ Xout)
{
    __shared__ __align__(16) char smem[49152];
    bf16* Xs = (bf16*)smem;                           // 64 x 256 (32 slots/row)
    bf16* Ts = (bf16*)(smem + 32768);                 // 64 x 128 (16 slots/row)
    float2 (*red)[2] = (float2 (*)[2])(void*)(smem + 32768);   // aliases Ts

    const int tid  = threadIdx.x;
    const int lane = tid & 63;
    const int wv   = tid >> 6;
    const int wm   = wv >> 1;
    const int wn   = wv & 1;
    const int quad = lane >> 4;
    const int l16  = lane & 15;
    const int bm   = blockIdx.x * 64;

#pragma unroll
    for (int it = 0; it < 8; ++it) {
        const int L = it * 256 + tid;
        const int row = L >> 5, slot = L & 31;
        const int gch = (slot & 24) | ((slot ^ row) & 7);
        async_copy16(X + (size_t)(bm + row) * 256 + gch * 8,
                     (char*)Xs + (size_t)L * 16);
    }
    __syncthreads();

    f32x4 acc2[2][8] = {};

#pragma unroll 1
    for (int hc = 0; hc < 8; ++hc) {
        f32x4 accA[2][4] = {};

        // ---- phase A: accA = Xs @ W1c^T (fragments direct, unroll 2)
#pragma unroll 2
        for (int kk = 0; kk < 8; ++kk) {
            bf16x8 af[2], bfr[4];
            const int gc = kk * 4 + quad;
#pragma unroll
            for (int i = 0; i < 2; ++i) {
                const int m  = wm * 32 + i * 16 + l16;
                const int sl = (gc & 24) | ((gc ^ m) & 7);
                af[i] = *(const bf16x8*)((const char*)Xs + (m * 32 + sl) * 16);
            }
#pragma unroll
            for (int j = 0; j < 4; ++j) {
                const int nt = hc * 8 + wn * 4 + j;
                bfr[j] = *(const bf16x8*)(W1f + ((size_t)(nt * 8 + kk) * 64 + lane) * 8);
            }
#pragma unroll
            for (int i = 0; i < 2; ++i)
#pragma unroll
                for (int j = 0; j < 4; ++j)
                    accA[i][j] = __builtin_amdgcn_mfma_f32_16x16x32_bf16(
                        af[i], bfr[j], accA[i][j], 0, 0, 0);
        }

        __syncthreads();   // all waves' prev-hc phase-B Ts reads done

        // ---- Ts = relu(accA + b1)
#pragma unroll
        for (int j = 0; j < 4; ++j) {
            const int h  = wn * 64 + j * 16 + l16;
            const float bb = b1[hc * 128 + h];
            const int g  = h >> 3;
#pragma unroll
            for (int i = 0; i < 2; ++i)
#pragma unroll
                for (int r = 0; r < 4; ++r) {
                    const int m  = wm * 32 + i * 16 + quad * 4 + r;
                    const int sl = (g & 8) | ((g ^ m) & 7);
                    const float v = fmaxf(accA[i][j][r] + bb, 0.f);
                    *((bf16*)((char*)Ts + (m * 16 + sl) * 16 + (h & 7) * 2)) = (bf16)v;
                }
        }
        __syncthreads();

        // ---- phase B: acc2 += Ts @ W2c^T (fragments direct, unroll 2)
#pragma unroll 2
        for (int kc = 0; kc < 4; ++kc) {
            const int tc = kc * 4 + quad;
            bf16x8 af[2], bfr[8];
#pragma unroll
            for (int i = 0; i < 2; ++i) {
                const int m  = wm * 32 + i * 16 + l16;
                const int sl = (tc & 8) | ((tc ^ m) & 7);
                af[i] = *(const bf16x8*)((const char*)Ts + (m * 16 + sl) * 16);
            }
            const int kcg = hc * 4 + kc;
#pragma unroll
            for (int j = 0; j < 8; ++j) {
                const int nt = wn * 8 + j;
                bfr[j] = *(const bf16x8*)(W2f + ((size_t)(nt * 32 + kcg) * 64 + lane) * 8);
            }
#pragma unroll
            for (int i = 0; i < 2; ++i)
#pragma unroll
                for (int j = 0; j < 8; ++j)
                    acc2[i][j] = __builtin_amdgcn_mfma_f32_16x16x32_bf16(
                        af[i], bfr[j], acc2[i][j], 0, 0, 0);
        }
    }

    __syncthreads();   // last Ts reads before red[] aliases it

    float bv[8], gv[8], bev[8];
#pragma unroll
    for (int j = 0; j < 8; ++j) {
        const int n = wn * 128 + j * 16 + l16;
        bv[j] = b2[n]; gv[j] = gam[n]; bev[j] = bet[n];
    }

#pragma unroll
    for (int i = 0; i < 2; ++i) {
#pragma unroll
        for (int r = 0; r < 4; ++r) {
            const int rl = wm * 32 + i * 16 + quad * 4 + r;
            float s1 = 0.f, s2 = 0.f;
#pragma unroll
            for (int j = 0; j < 8; ++j) {
                const int n  = wn * 128 + j * 16 + l16;
                const int gc = n >> 3;
                const int sl = (gc & 24) | ((gc ^ rl) & 7);
                const float xr = (float)*((const bf16*)((const char*)Xs +
                                   (rl * 32 + sl) * 16 + (n & 7) * 2));
                const float v = acc2[i][j][r] + bv[j] + xr;
                acc2[i][j][r] = v;
                s1 += v; s2 += v * v;
            }
#pragma unroll
            for (int off = 1; off < 16; off <<= 1) {
                s1 += __shfl_xor(s1, off, 64);
                s2 += __shfl_xor(s2, off, 64);
            }
            if (l16 == 0) red[rl][wn] = make_float2(s1, s2);
        }
    }
    __syncthreads();

#pragma unroll
    for (int i = 0; i < 2; ++i) {
#pragma unroll
        for (int r = 0; r < 4; ++r) {
            const int rl = wm * 32 + i * 16 + quad * 4 + r;
            const float2 p0 = red[rl][0], p1 = red[rl][1];
            const float mu  = (p0.x + p1.x) * (1.f / 256.f);
            const float ex2 = (p0.y + p1.y) * (1.f / 256.f);
            const float rstd = rsqrtf(fmaxf(ex2 - mu * mu, 0.f) + 1e-5f);
            const size_t row = (size_t)(bm + rl);
#pragma unroll
            for (int j = 0; j < 8; ++j) {
                const int n = wn * 128 + j * 16 + l16;
                Xout[row * 256 + n] = (bf16)((acc2[i][j][r] - mu) * rstd * gv[j] + bev[j]);
            }
        }
    }
}

// --------------------------------------------------------------------------
// attention v2: per sequence (4 tokens), 8 heads x dh=32, softmax over 4.
// --------------------------------------------------------------------------
__global__ __launch_bounds__(256) void attention_k(const bf16* __restrict__ QKV,
                                                   bf16* __restrict__ SA)
{
    __shared__ float qf[4][4][768];
    __shared__ float sc[4][8][4][4];

    const int tid  = threadIdx.x;
    const int wv   = tid >> 6;
    const int lane = tid & 63;
    const int s    = blockIdx.x * 4 + wv;

    const bf16* base = QKV + (size_t)s * 4 * 768;
#pragma unroll
    for (int it = 0; it < 6; ++it) {
        const int idx = it * 64 + lane;
        const bf16x8 v = *(const bf16x8*)(base + idx * 8);
        const int tok = idx / 96;
        const int e   = (idx % 96) * 8;
        f32x4 f0, f1;
#pragma unroll
        for (int i = 0; i < 4; ++i) { f0[i] = (float)v[i]; f1[i] = (float)v[4 + i]; }
        *(f32x4*)(&qf[wv][tok][e])     = f0;
        *(f32x4*)(&qf[wv][tok][e + 4]) = f1;
    }
    __syncthreads();

#pragma unroll
    for (int rep = 0; rep < 2; ++rep) {
        const int t = rep * 64 + lane;
        const int h = t >> 4, i = (t >> 2) & 3, j = t & 3;
        const float* q = &qf[wv][i][h * 32];
        const float* k = &qf[wv][j][256 + h * 32];
        float a = 0.f;
#pragma unroll
        for (int dd = 0; dd < 32; ++dd) {
            const int d = (dd + lane) & 31;
            a += q[d] * k[d];
        }
        sc[wv][h][i][j] = a * 0.17677669529663687f;
    }
    __syncthreads();

    if (lane < 32) {
        const int h = lane >> 2, i = lane & 3;
        float s0 = sc[wv][h][i][0], s1 = sc[wv][h][i][1];
        float s2 = sc[wv][h][i][2], s3 = sc[wv][h][i][3];
        float m = fmaxf(fmaxf(s0, s1), fmaxf(s2, s3));
        float e0 = expf(s0 - m), e1 = expf(s1 - m);
        float e2 = expf(s2 - m), e3 = expf(s3 - m);
        float inv = 1.f / (e0 + e1 + e2 + e3);
        sc[wv][h][i][0] = e0 * inv;
        sc[wv][h][i][1] = e1 * inv;
        sc[wv][h][i][2] = e2 * inv;
        sc[wv][h][i][3] = e3 * inv;
    }
    __syncthreads();

    const int h = lane >> 3;
#pragma unroll
    for (int i = 0; i < 4; ++i) {
        f32x4 a = {0.f, 0.f, 0.f, 0.f};
#pragma unroll
        for (int j = 0; j < 4; ++j) {
            const float p = sc[wv][h][i][j];
            const f32x4 v = *(const f32x4*)(&qf[wv][j][512 + lane * 4]);
#pragma unroll
            for (int q = 0; q < 4; ++q) a[q] += p * v[q];
        }
        bf16x4 o;
#pragma unroll
        for (int q = 0; q < 4; ++q) o[q] = (bf16)a[q];
        *(bf16x4*)(SA + (size_t)(s * 4 + i) * 256 + lane * 4) = o;
    }
}

// --------------------------------------------------------------------------
// out[b][c][hw] = sum_e (mean_cam X[p*4+cam][e]) * Wout[c][e] + bout[c]
// --------------------------------------------------------------------------
__global__ __launch_bounds__(256) void out_proj_k(const bf16* __restrict__ X,
                                                  const float* __restrict__ Wout,
                                                  const float* __restrict__ bout,
                                                  float* __restrict__ out)
{
    __shared__ float fused[16][260];
    const int tid = threadIdx.x;
    const int p0  = blockIdx.x * 16;

#pragma unroll
    for (int it = 0; it < 16; ++it) {
        const int idx = it * 256 + tid;
        const int pix = idx >> 8, e = idx & 255;
        const size_t base = (size_t)(p0 + pix) * 1024 + e;
        const float s = (float)X[base] + (float)X[base + 256] +
                        (float)X[base + 512] + (float)X[base + 768];
        fused[pix][e] = s * 0.25f;
    }
    __syncthreads();

    const int pix = tid & 15;
    const int c0  = tid >> 4;
    const int p   = p0 + pix;
    const int b   = p / 9216;
    const int hw  = p % 9216;
#pragma unroll
    for (int it = 0; it < 4; ++it) {
        const int c = it * 16 + c0;
        const float* w = Wout + c * 256;
        float acc = bout[c];
#pragma unroll 8
        for (int e = 0; e < 256; ++e) acc += fused[pix][e] * w[e];
        out[((size_t)b * 64 + c) * 9216 + hw] = acc;
    }
}

// --------------------------------------------------------------------------
extern "C" void kernel_launch(void* const* d_in, const int* in_sizes, int n_in,
                              void* d_out, int out_size, void* d_ws, size_t ws_size,
                              hipStream_t stream)
{
    const float* features = (const float*)d_in[0];
    const float* Wp   = (const float*)d_in[1];
    const float* bp   = (const float*)d_in[2];
    const float* Wqkv = (const float*)d_in[3];
    const float* bqkv = (const float*)d_in[4];
    const float* Wo   = (const float*)d_in[5];
    const float* bo   = (const float*)d_in[6];
    const float* W1   = (const float*)d_in[7];
    const float* b1   = (const float*)d_in[8];
    const float* W2   = (const float*)d_in[9];
    const float* b2   = (const float*)d_in[10];
    const float* g1   = (const float*)d_in[11];
    const float* be1  = (const float*)d_in[12];
    const float* g2   = (const float*)d_in[13];
    const float* be2  = (const float*)d_in[14];
    const float* Wout = (const float*)d_in[15];
    const float* bout = (const float*)d_in[16];
    float* out = (float*)d_out;

    char* ws = (char*)d_ws;
    bf16* X     = (bf16*)(ws);                    // 73728*256
    bf16* QKV   = (bf16*)(ws + 37748736ull);      // 73728*768
    bf16* SAb   = (bf16*)(ws + 150994944ull);     // 73728*256
    bf16* Xf    = (bf16*)(ws + 188743680ull);     // 73728*64
    bf16* WpB   = (bf16*)(ws + 198180864ull);     // 256*64 row-major
    bf16* W2F   = (bf16*)(ws + 198213632ull);     // 2 x 262144 fragments
    bf16* W1F   = (bf16*)(ws + 199262208ull);     // 2 x 262144 fragments
    bf16* WqkvF = (bf16*)(ws + 200310784ull);     // 2 x 196608 fragments
    bf16* WoB   = (bf16*)(ws + 226492416ull);     // 2 x 256*256 row-major

    pack_all_k<<<576, 256, 0, stream>>>(Wo, Wp, WoB, WpB);
    pack_frag_k<<<704, 256, 0, stream>>>(W1, W2, Wqkv, W1F, W2F, WqkvF);

    feat_pack_k<<<dim3(144, 8), 256, 0, stream>>>(features, Xf);
    gemm_bt<false><<<dim3(2, 576), 256, 0, stream>>>(Xf, WpB, bp, X, 256, 64);

    for (int l = 0; l < 2; ++l) {
        gemm_qkv_k<<<dim3(6, 576), 256, 0, stream>>>(
            X, WqkvF + l * 196608, bqkv + l * 768, QKV);
        attention_k<<<4608, 256, 0, stream>>>(QKV, SAb);
        gemm_ln_k<<<576, 256, 0, stream>>>(
            SAb, WoB + l * 65536, bo + l * 256, X,
            g1 + l * 256, be1 + l * 256, X, 256);
        ffn_fused_k<<<1152, 256, 0, stream>>>(
            X, W1F + l * 262144, b1 + l * 1024,
            W2F + l * 262144, b2 + l * 256,
            g2 + l * 256, be2 + l * 256, X);
    }

    out_proj_k<<<1152, 256, 0, stream>>>(X, Wout, bout, out);
}